// Round 8
// baseline (355.272 us; speedup 1.0000x reference)
//
#include <hip/hip_runtime.h>

#define B_ 4
#define H_ 8
#define L_ 2048
#define DM 512
#define DK 64

typedef __bf16 bf16x8 __attribute__((ext_vector_type(8)));
typedef float f32x4 __attribute__((ext_vector_type(4)));

__device__ __forceinline__ f32x4 mfma16(bf16x8 a, bf16x8 b, f32x4 c) {
  return __builtin_amdgcn_mfma_f32_16x16x32_bf16(a, b, c, 0, 0, 0);
}
__device__ __forceinline__ unsigned short f2bf(float f) {
  unsigned int u = __float_as_uint(f);
  u += 0x7fffu + ((u >> 16) & 1u);
  return (unsigned short)(u >> 16);
}
__device__ __forceinline__ float fexp2(float x) {
  float r;
  asm("v_exp_f32 %0, %1" : "=v"(r) : "v"(x));
  return r;
}
__device__ __forceinline__ void async16(const void* g, void* l) {
  __builtin_amdgcn_global_load_lds((const __attribute__((address_space(1))) unsigned int*)g,
                                   (__attribute__((address_space(3))) unsigned int*)l, 16, 0, 0);
}
__device__ __forceinline__ float rsum16(float v) {
  v += __shfl_xor(v, 1);
  v += __shfl_xor(v, 2);
  v += __shfl_xor(v, 4);
  v += __shfl_xor(v, 8);
  return v;
}

// D = X(64x64, stride 65) @ Y(64x64, stride 65); thread computes 4x4 tile.
__device__ __forceinline__ void mm64(const float* X, const float* Y, float acc[4][4], int tr, int tc) {
#pragma unroll
  for (int rr = 0; rr < 4; ++rr)
#pragma unroll
    for (int cc = 0; cc < 4; ++cc) acc[rr][cc] = 0.f;
  for (int c = 0; c < 64; ++c) {
    float a0 = X[(tr + 0) * 65 + c], a1 = X[(tr + 1) * 65 + c];
    float a2 = X[(tr + 2) * 65 + c], a3 = X[(tr + 3) * 65 + c];
    float b0 = Y[c * 65 + tc + 0], b1 = Y[c * 65 + tc + 1];
    float b2 = Y[c * 65 + tc + 2], b3 = Y[c * 65 + tc + 3];
    acc[0][0] += a0 * b0; acc[0][1] += a0 * b1; acc[0][2] += a0 * b2; acc[0][3] += a0 * b3;
    acc[1][0] += a1 * b0; acc[1][1] += a1 * b1; acc[1][2] += a1 * b2; acc[1][3] += a1 * b3;
    acc[2][0] += a2 * b0; acc[2][1] += a2 * b1; acc[2][2] += a2 * b2; acc[2][3] += a2 * b3;
    acc[3][0] += a3 * b0; acc[3][1] += a3 * b1; acc[3][2] += a3 * b2; acc[3][3] += a3 * b3;
  }
}

// Per head: Wq = A*A*A2*A2, Wv = Av*Av  (64x64 each, f32)
__global__ __launch_bounds__(256) void k_weights(const float* __restrict__ WA, const float* __restrict__ WA2,
                                                 const float* __restrict__ WA3, float* __restrict__ Wq,
                                                 float* __restrict__ Wv) {
  __shared__ float sA[64 * 65], sB[64 * 65], sT[64 * 65];
  const int h = blockIdx.x, t = threadIdx.x;
  const int tr = (t >> 4) * 4, tc = (t & 15) * 4;
  for (int i = t; i < 4096; i += 256) {
    int r = i >> 6, c = i & 63;
    sA[r * 65 + c] = WA[h * 4096 + i];
    sB[r * 65 + c] = WA2[h * 4096 + i];
  }
  __syncthreads();
  float acc[4][4];
  mm64(sA, sA, acc, tr, tc);
#pragma unroll
  for (int rr = 0; rr < 4; ++rr)
#pragma unroll
    for (int cc = 0; cc < 4; ++cc) sT[(tr + rr) * 65 + tc + cc] = acc[rr][cc];
  __syncthreads();
  mm64(sT, sB, acc, tr, tc);
#pragma unroll
  for (int rr = 0; rr < 4; ++rr)
#pragma unroll
    for (int cc = 0; cc < 4; ++cc) sA[(tr + rr) * 65 + tc + cc] = acc[rr][cc];
  __syncthreads();
  mm64(sA, sB, acc, tr, tc);
#pragma unroll
  for (int rr = 0; rr < 4; ++rr)
#pragma unroll
    for (int cc = 0; cc < 4; ++cc) Wq[h * 4096 + (tr + rr) * 64 + tc + cc] = acc[rr][cc];
  for (int i = t; i < 4096; i += 256) {
    int r = i >> 6, c = i & 63;
    sT[r * 65 + c] = WA3[h * 4096 + i];
  }
  __syncthreads();
  mm64(sT, sT, acc, tr, tc);
#pragma unroll
  for (int rr = 0; rr < 4; ++rr)
#pragma unroll
    for (int cc = 0; cc < 4; ++cc) Wv[h * 4096 + (tr + rr) * 64 + tc + cc] = acc[rr][cc];
}

// f32 -> bf16 elementwise (vec4)
__global__ void k_conv(const float* __restrict__ s, unsigned short* __restrict__ d, int n4) {
  int i = blockIdx.x * blockDim.x + threadIdx.x;
  int stride = gridDim.x * blockDim.x;
  for (; i < n4; i += stride) {
    float4 f = ((const float4*)s)[i];
    ushort4 o;
    o.x = f2bf(f.x); o.y = f2bf(f.y); o.z = f2bf(f.z); o.w = f2bf(f.w);
    ((ushort4*)d)[i] = o;
  }
}

// mask int32 [b,row,key] -> bitmask u64 words [b*L+row][32]
__global__ __launch_bounds__(256) void k_maskpack(const int* __restrict__ mask,
                                                  unsigned long long* __restrict__ mp) {
  const int row = blockIdx.x * 4 + (threadIdx.x >> 6);
  const int lane = threadIdx.x & 63;
  const int* src = mask + (size_t)row * L_;
#pragma unroll
  for (int c = 0; c < 32; ++c) {
    int mv = src[c * 64 + lane];
    unsigned long long bits = __ballot(mv != 0);
    if (lane == 0) mp[(size_t)row * 32 + c] = bits;
  }
}

// Q'[b,row,h*64+dk] = (q_head @ Wq[h]) * (1/8)*log2(e), bf16  (exp2-folded scale)
__global__ __launch_bounds__(256) void k_qprime(const float* __restrict__ q, const float* __restrict__ Wq,
                                                unsigned short* __restrict__ Qp) {
  __shared__ float sW[64 * 65], sQ[64 * 65];
  const int bid = blockIdx.x;
  const int rt = bid & 31, h = (bid >> 5) & 7, b = bid >> 8;
  const int t = threadIdx.x;
  const int row0 = rt * 64;
  const float QS = 0.125f * 1.44269504088896f;
  for (int i = t; i < 4096; i += 256) {
    int r = i >> 6, c = i & 63;
    sW[r * 65 + c] = Wq[h * 4096 + i];
    sQ[r * 65 + c] = q[(size_t)(b * L_ + row0 + r) * DM + h * DK + c];
  }
  __syncthreads();
  float acc[4][4];
  const int tr = (t >> 4) * 4, tc = (t & 15) * 4;
  mm64(sQ, sW, acc, tr, tc);
#pragma unroll
  for (int rr = 0; rr < 4; ++rr) {
    ushort4 o;
    o.x = f2bf(acc[rr][0] * QS); o.y = f2bf(acc[rr][1] * QS);
    o.z = f2bf(acc[rr][2] * QS); o.w = f2bf(acc[rr][3] * QS);
    *(ushort4*)&Qp[(size_t)(b * L_ + row0 + tr + rr) * DM + h * DK + tc] = o;
  }
}

// V'T[b,h,dk,key] = (v_head @ Wv[h])^T, bf16
__global__ __launch_bounds__(256) void k_vprime(const float* __restrict__ v, const float* __restrict__ Wv,
                                                unsigned short* __restrict__ VpT) {
  __shared__ float sW[64 * 65], sV[64 * 65];
  __shared__ __align__(16) unsigned short ldsT[64 * 72];
  const int bid = blockIdx.x;
  const int rt = bid & 31, h = (bid >> 5) & 7, b = bid >> 8;
  const int t = threadIdx.x;
  const int key0 = rt * 64;
  for (int i = t; i < 4096; i += 256) {
    int r = i >> 6, c = i & 63;
    sW[r * 65 + c] = Wv[h * 4096 + i];
    sV[r * 65 + c] = v[(size_t)(b * L_ + key0 + r) * DM + h * DK + c];
  }
  __syncthreads();
  float acc[4][4];
  const int tr = (t >> 4) * 4, tc = (t & 15) * 4;
  mm64(sV, sW, acc, tr, tc);   // [key][dk]
#pragma unroll
  for (int rr = 0; rr < 4; ++rr)
#pragma unroll
    for (int cc = 0; cc < 4; ++cc) ldsT[(tc + cc) * 72 + tr + rr] = f2bf(acc[rr][cc]);
  __syncthreads();
  const int dk = t >> 2, kc = t & 3;
  const uint4* srcp = (const uint4*)&ldsT[dk * 72 + kc * 16];
  uint4 v0 = srcp[0], v1 = srcp[1];
  size_t go = ((size_t)((b * H_ + h) * DK + dk)) * L_ + key0 + kc * 16;
  *(uint4*)&VpT[go] = v0;
  *(uint4*)&VpT[go + 8] = v1;
}

// Fused attention, S^T swapped layout.
// Pass 1: barrier-free, LDS-free — direct L2 fragment loads with one-tile
// register lookahead (F/G ping-pong, static indexing). Compiler inserts the
// counted vmcnt per register dependency; 4 independent waves/SIMD hide L2 lat.
// Pass 2: R7 structure — dbuf global_load_lds staging, raw barriers + counted
// vmcnt, nontemporal float4 P stores. LDS 36KB -> 4 blocks/CU.
__global__ __launch_bounds__(256, 4) void k_attn(const unsigned short* __restrict__ Qp,
                                                 const unsigned short* __restrict__ Kb,
                                                 const unsigned short* __restrict__ VpT,
                                                 const unsigned long long* __restrict__ mp,
                                                 float* __restrict__ attn,
                                                 float* __restrict__ ov) {
  __shared__ __align__(16) unsigned short KT[2][4096];  // 64 keys x 64 dk, swizzled
  __shared__ __align__(16) unsigned short VT[2][4096];  // 64 dk x 64 keys, swizzled
  __shared__ __align__(16) unsigned short PB[4][1024];  // per-wave P, [16 qrows][64 keys] swz
  const int bid0 = blockIdx.x;
  const int bid = (bid0 & 7) * 128 + (bid0 >> 3);  // XCD swizzle (1024 % 8 == 0)
  const int qt = bid & 31;
  const int h = (bid >> 5) & 7;
  const int b = bid >> 8;
  const int tid = threadIdx.x;
  const int lane = tid & 63;
  const int w = tid >> 6;
  const int l15 = lane & 15, l4 = lane >> 4;
  const int row0 = qt * 64 + w * 16;

  const unsigned short* qb = Qp + ((size_t)(b * L_ + row0 + l15)) * DM + h * DK + l4 * 8;
  const bf16x8 aQ0 = *(const bf16x8*)qb;
  const bf16x8 aQ1 = *(const bf16x8*)(qb + 32);

  const size_t kb_base = (size_t)b * L_ * DM + h * DK;
  const size_t vt_base = (size_t)((b * H_ + h) * DK) * L_;
  // per-lane mask row = this lane's q-row (l15)
  const unsigned long long* mrowl = mp + (size_t)(b * L_ + row0 + l15) * 32;

  float lsum = 0.f;

  // ================= Pass 1: denominators (no LDS, no barriers) =================
  {
    const unsigned short* kfrag = Kb + kb_base + (size_t)l15 * DM + l4 * 8;
    bf16x8 F[8], G[8];
    unsigned long long m0, m1, n0, n1;

#define LOADF(FR, kt_)                                                                     \
    {                                                                                      \
      _Pragma("unroll") for (int f = 0; f < 4; ++f) {                                      \
        const unsigned short* kp = kfrag + (size_t)((kt_) * 64 + f * 16) * DM;             \
        FR[2 * f] = *(const bf16x8*)kp;                                                    \
        FR[2 * f + 1] = *(const bf16x8*)(kp + 32);                                         \
      }                                                                                    \
    }
#define COMPF(FR, MW)                                                                      \
    {                                                                                      \
      _Pragma("unroll") for (int f = 0; f < 4; ++f) {                                      \
        f32x4 acc = {0.f, 0.f, 0.f, 0.f};                                                  \
        acc = mfma16(FR[2 * f], aQ0, acc);                                                 \
        acc = mfma16(FR[2 * f + 1], aQ1, acc);                                             \
        unsigned nib = (unsigned)((MW) >> (f * 16 + l4 * 4));                              \
        _Pragma("unroll") for (int r = 0; r < 4; ++r)                                      \
          lsum += ((nib >> r) & 1u) ? fexp2(acc[r]) : 0.f;                                 \
      }                                                                                    \
    }

    LOADF(F, 0);
    m0 = mrowl[0];
    m1 = mrowl[1];
    for (int j = 0; j < 16; ++j) {
      const int kt = j * 2;
      LOADF(G, kt + 1);
      if (j < 15) { n0 = mrowl[kt + 2]; n1 = mrowl[kt + 3]; }
      else        { n0 = 0ull; n1 = 0ull; }
      COMPF(F, m0);
      if (j < 15) LOADF(F, kt + 2);
      COMPF(G, m1);
      m0 = n0; m1 = n1;
    }
#undef LOADF
#undef COMPF
  }

  // q-row l15's total: reduce over the 4 lanes (l4) holding this row
  lsum += __shfl_xor(lsum, 16);
  lsum += __shfl_xor(lsum, 32);
  const float invl = 1.0f / lsum;

  f32x4 O[4];
#pragma unroll
  for (int d = 0; d < 4; ++d) { f32x4 z = {0.f, 0.f, 0.f, 0.f}; O[d] = z; }

  float* arowl = attn + ((size_t)((b * H_ + h) * L_) + row0 + l15) * L_;
  char* pbw = (char*)&PB[w][0];
  const int psw = (l15 & 7) << 4;

  // staging: linear LDS dest (tid*16), inverse-swizzled global source
  const int p_lo = tid * 16;
  const int skey = p_lo >> 7;
  const int sboff = (p_lo & 127) ^ ((skey & 7) << 4);
  const int skey1 = (p_lo + 4096) >> 7;
  const int sboff1 = ((p_lo + 4096) & 127) ^ ((skey1 & 7) << 4);

#define STAGE_K(kt_, s_)                                                                   \
  {                                                                                        \
    async16(Kb + kb_base + (size_t)((kt_) * 64 + skey) * DM + (sboff >> 1),                \
            (char*)&KT[s_][0] + p_lo);                                                     \
    async16(Kb + kb_base + (size_t)((kt_) * 64 + skey1) * DM + (sboff1 >> 1),              \
            (char*)&KT[s_][0] + p_lo + 4096);                                              \
  }
#define STAGE_V(kt_, s_)                                                                   \
  {                                                                                        \
    async16(VpT + vt_base + (size_t)skey * L_ + (kt_) * 64 + (sboff >> 1),                 \
            (char*)&VT[s_][0] + p_lo);                                                     \
    async16(VpT + vt_base + (size_t)skey1 * L_ + (kt_) * 64 + (sboff1 >> 1),               \
            (char*)&VT[s_][0] + p_lo + 4096);                                              \
  }

  // ================= Pass 2: P write + PV =================
  unsigned long long mwA, mwB;
  mwA = mrowl[0];
  mwB = mrowl[1];
  STAGE_K(0, 0);
  STAGE_V(0, 0);
  asm volatile("s_waitcnt vmcnt(0)" ::: "memory");
  __builtin_amdgcn_s_barrier();

#define P2_BODY(KT_, VMN_, DO_STAGE_, DO_LOADM_)                                           \
  {                                                                                        \
    const int kt = (KT_);                                                                  \
    const int cur = kt & 1;                                                                \
    const int key0 = kt * 64;                                                              \
    __builtin_amdgcn_sched_barrier(0);                                                     \
    unsigned long long mwN = 0ull;                                                         \
    if (DO_LOADM_) mwN = mrowl[kt + 2];                                                    \
    if (DO_STAGE_) { STAGE_K(kt + 1, cur ^ 1); STAGE_V(kt + 1, cur ^ 1); }                 \
    asm volatile("s_waitcnt vmcnt(" #VMN_ ")" ::: "memory");                               \
    __builtin_amdgcn_sched_barrier(0);                                                     \
    __builtin_amdgcn_s_barrier();                                                          \
    const char* Kbase = (const char*)&KT[cur][0];                                          \
    const char* Vbase = (const char*)&VT[cur][0];                                          \
    float pvv[4][4];                                                                       \
    _Pragma("unroll") for (int f = 0; f < 4; ++f) {                                        \
      int keyrow = f * 16 + l15;                                                           \
      int sw = (keyrow & 7) << 4;                                                          \
      bf16x8 b0 = *(const bf16x8*)(Kbase + keyrow * 128 + ((l4 * 16) ^ sw));               \
      bf16x8 b1 = *(const bf16x8*)(Kbase + keyrow * 128 + ((64 + l4 * 16) ^ sw));          \
      f32x4 acc = {0.f, 0.f, 0.f, 0.f};                                                    \
      acc = mfma16(b0, aQ0, acc);                                                          \
      acc = mfma16(b1, aQ1, acc);                                                          \
      unsigned nib = (unsigned)(mwA >> (f * 16 + l4 * 4));                                 \
      _Pragma("unroll") for (int r = 0; r < 4; ++r)                                        \
        pvv[f][r] = ((nib >> r) & 1u) ? fexp2(acc[r]) * invl : 0.f;                        \
    }                                                                                      \
    _Pragma("unroll") for (int f = 0; f < 4; ++f) {                                        \
      f32x4 sv;                                                                            \
      sv[0] = pvv[f][0]; sv[1] = pvv[f][1]; sv[2] = pvv[f][2]; sv[3] = pvv[f][3];          \
      __builtin_nontemporal_store(sv, (f32x4*)(arowl + key0 + f * 16 + l4 * 4));           \
    }                                                                                      \
    _Pragma("unroll") for (int f = 0; f < 4; ++f) {                                        \
      ushort4 pk;                                                                          \
      pk.x = f2bf(pvv[f][0]); pk.y = f2bf(pvv[f][1]);                                      \
      pk.z = f2bf(pvv[f][2]); pk.w = f2bf(pvv[f][3]);                                      \
      *(ushort4*)(pbw + l15 * 128 + ((f * 32 + l4 * 8) ^ psw)) = pk;                       \
    }                                                                                      \
    bf16x8 aP0 = *(const bf16x8*)(pbw + l15 * 128 + ((l4 * 16) ^ psw));                    \
    bf16x8 aP1 = *(const bf16x8*)(pbw + l15 * 128 + ((64 + l4 * 16) ^ psw));               \
    __builtin_amdgcn_s_setprio(1);                                                         \
    _Pragma("unroll") for (int d = 0; d < 4; ++d) {                                        \
      int dkrow = d * 16 + l15;                                                            \
      int sw = (dkrow & 7) << 4;                                                           \
      bf16x8 v0 = *(const bf16x8*)(Vbase + dkrow * 128 + ((l4 * 16) ^ sw));                \
      bf16x8 v1 = *(const bf16x8*)(Vbase + dkrow * 128 + ((64 + l4 * 16) ^ sw));           \
      O[d] = mfma16(aP0, v0, O[d]);                                                        \
      O[d] = mfma16(aP1, v1, O[d]);                                                        \
    }                                                                                      \
    __builtin_amdgcn_s_setprio(0);                                                         \
    __builtin_amdgcn_s_barrier();                                                          \
    mwA = mwB; mwB = mwN;                                                                  \
  }

  for (int t = 0; t < 30; ++t) P2_BODY(t, 9, true, true);
  P2_BODY(30, 8, true, false);
  P2_BODY(31, 4, false, false);
#undef P2_BODY

#pragma unroll
  for (int d = 0; d < 4; ++d)
#pragma unroll
    for (int r = 0; r < 4; ++r)
      ov[(size_t)(b * L_ + row0 + l4 * 4 + r) * DM + h * DK + d * 16 + l15] = O[d][r];
#undef STAGE_K
#undef STAGE_V
}

// out = LN(O @ fc^T + q) in place on d_out rows. Block = 16 token rows, wave = 128 cols.
__global__ __launch_bounds__(256) void k_proj(const float* __restrict__ qres,
                                              const unsigned short* __restrict__ fcb,
                                              const float* __restrict__ gamma,
                                              const float* __restrict__ beta,
                                              float* __restrict__ io) {
  __shared__ float red1[16][4], red2[16][4];
  const int blk = blockIdx.x;
  const int tid = threadIdx.x, lane = tid & 63, w = tid >> 6;
  const int l15 = lane & 15, l4 = lane >> 4;
  const int row0 = blk * 16;
  const float* arow = io + (size_t)(row0 + l15) * DM + l4 * 8;
  const unsigned short* bb = fcb + (size_t)(w * 128 + l15) * DM + l4 * 8;
  f32x4 C[8];
#pragma unroll
  for (int i = 0; i < 8; ++i) { f32x4 z = {0.f, 0.f, 0.f, 0.f}; C[i] = z; }
  for (int kc = 0; kc < 16; ++kc) {
    float4 a0 = *(const float4*)(arow + kc * 32);
    float4 a1 = *(const float4*)(arow + kc * 32 + 4);
    union { unsigned short u[8]; bf16x8 v; } t;
    t.u[0] = f2bf(a0.x); t.u[1] = f2bf(a0.y); t.u[2] = f2bf(a0.z); t.u[3] = f2bf(a0.w);
    t.u[4] = f2bf(a1.x); t.u[5] = f2bf(a1.y); t.u[6] = f2bf(a1.z); t.u[7] = f2bf(a1.w);
#pragma unroll
    for (int cf = 0; cf < 8; ++cf) {
      bf16x8 bv = *(const bf16x8*)(bb + (size_t)(cf * 16) * DM + kc * 32);
      C[cf] = mfma16(t.v, bv, C[cf]);
    }
  }
  float s1[4] = {0.f, 0.f, 0.f, 0.f}, s2[4] = {0.f, 0.f, 0.f, 0.f};
  const int colb = w * 128;
#pragma unroll
  for (int cf = 0; cf < 8; ++cf)
#pragma unroll
    for (int r = 0; r < 4; ++r) {
      float val = C[cf][r] + qres[(size_t)(row0 + l4 * 4 + r) * DM + colb + cf * 16 + l15];
      C[cf][r] = val;
      s1[r] += val;
      s2[r] += val * val;
    }
#pragma unroll
  for (int r = 0; r < 4; ++r) { s1[r] = rsum16(s1[r]); s2[r] = rsum16(s2[r]); }
  if (l15 == 0) {
#pragma unroll
    for (int r = 0; r < 4; ++r) { red1[l4 * 4 + r][w] = s1[r]; red2[l4 * 4 + r][w] = s2[r]; }
  }
  __syncthreads();
  float mu[4], rs[4];
#pragma unroll
  for (int r = 0; r < 4; ++r) {
    int row = l4 * 4 + r;
    float t1 = red1[row][0] + red1[row][1] + red1[row][2] + red1[row][3];
    float t2 = red2[row][0] + red2[row][1] + red2[row][2] + red2[row][3];
    float m_ = t1 * (1.0f / 512.0f);
    float var = t2 * (1.0f / 512.0f) - m_ * m_;
    mu[r] = m_;
    rs[r] = rsqrtf(var + 1e-6f);
  }
#pragma unroll
  for (int cf = 0; cf < 8; ++cf) {
    float g = gamma[colb + cf * 16 + l15];
    float be = beta[colb + cf * 16 + l15];
#pragma unroll
    for (int r = 0; r < 4; ++r)
      io[(size_t)(row0 + l4 * 4 + r) * DM + colb + cf * 16 + l15] =
          (C[cf][r] - mu[r]) * rs[r] * g + be;
  }
}

extern "C" void kernel_launch(void* const* d_in, const int* in_sizes, int n_in,
                              void* d_out, int out_size, void* d_ws, size_t ws_size,
                              hipStream_t stream) {
  (void)in_sizes; (void)n_in; (void)out_size; (void)ws_size;
  const float* q   = (const float*)d_in[0];
  const float* k   = (const float*)d_in[1];
  const float* v   = (const float*)d_in[2];
  const int* mask  = (const int*)d_in[3];
  const float* WA  = (const float*)d_in[4];
  const float* WA2 = (const float*)d_in[5];
  const float* WA3 = (const float*)d_in[6];
  const float* fcw = (const float*)d_in[7];
  const float* gam = (const float*)d_in[8];
  const float* bet = (const float*)d_in[9];
  float* out = (float*)d_out;
  float* attn = out + (size_t)B_ * L_ * DM;

  char* ws = (char*)d_ws;
  float* Wq = (float*)ws;                                               // 128KB
  float* Wv = (float*)(ws + 131072);                                    // 128KB
  unsigned short* Qp  = (unsigned short*)(ws + 262144);                 // 8MB
  unsigned short* Kb  = (unsigned short*)(ws + 262144 + 8388608);       // 8MB
  unsigned short* VpT = (unsigned short*)(ws + 262144 + 2 * 8388608);   // 8MB
  unsigned short* FCb = (unsigned short*)(ws + 262144 + 3 * 8388608);   // 512KB
  unsigned long long* mp = (unsigned long long*)(ws + 262144 + 3 * 8388608 + 524288);  // 2MB

  k_weights<<<8, 256, 0, stream>>>(WA, WA2, WA3, Wq, Wv);
  k_conv<<<1024, 256, 0, stream>>>(k, Kb, (B_ * L_ * DM) / 4);
  k_conv<<<256, 256, 0, stream>>>(fcw, FCb, (DM * DM) / 4);
  k_maskpack<<<2048, 256, 0, stream>>>(mask, mp);
  k_qprime<<<1024, 256, 0, stream>>>(q, Wq, Qp);
  k_vprime<<<1024, 256, 0, stream>>>(v, Wv, VpT);
  k_attn<<<1024, 256, 0, stream>>>(Qp, Kb, VpT, mp, attn, out);
  k_proj<<<512, 256, 0, stream>>>(q, FCb, gam, bet, out);
}

// Round 9
// 299.626 us; speedup vs baseline: 1.1857x; 1.1857x over previous
//
#include <hip/hip_runtime.h>

#define B_ 4
#define H_ 8
#define L_ 2048
#define DM 512
#define DK 64

typedef __bf16 bf16x8 __attribute__((ext_vector_type(8)));
typedef float f32x4 __attribute__((ext_vector_type(4)));

__device__ __forceinline__ f32x4 mfma16(bf16x8 a, bf16x8 b, f32x4 c) {
  return __builtin_amdgcn_mfma_f32_16x16x32_bf16(a, b, c, 0, 0, 0);
}
__device__ __forceinline__ unsigned short f2bf(float f) {
  unsigned int u = __float_as_uint(f);
  u += 0x7fffu + ((u >> 16) & 1u);
  return (unsigned short)(u >> 16);
}
__device__ __forceinline__ float fexp2(float x) {
  float r;
  asm("v_exp_f32 %0, %1" : "=v"(r) : "v"(x));
  return r;
}
__device__ __forceinline__ void async16(const void* g, void* l) {
  __builtin_amdgcn_global_load_lds((const __attribute__((address_space(1))) unsigned int*)g,
                                   (__attribute__((address_space(3))) unsigned int*)l, 16, 0, 0);
}
__device__ __forceinline__ float rsum16(float v) {
  v += __shfl_xor(v, 1);
  v += __shfl_xor(v, 2);
  v += __shfl_xor(v, 4);
  v += __shfl_xor(v, 8);
  return v;
}

// D = X(64x64, stride 65) @ Y(64x64, stride 65); thread computes 4x4 tile.
__device__ __forceinline__ void mm64(const float* X, const float* Y, float acc[4][4], int tr, int tc) {
#pragma unroll
  for (int rr = 0; rr < 4; ++rr)
#pragma unroll
    for (int cc = 0; cc < 4; ++cc) acc[rr][cc] = 0.f;
  for (int c = 0; c < 64; ++c) {
    float a0 = X[(tr + 0) * 65 + c], a1 = X[(tr + 1) * 65 + c];
    float a2 = X[(tr + 2) * 65 + c], a3 = X[(tr + 3) * 65 + c];
    float b0 = Y[c * 65 + tc + 0], b1 = Y[c * 65 + tc + 1];
    float b2 = Y[c * 65 + tc + 2], b3 = Y[c * 65 + tc + 3];
    acc[0][0] += a0 * b0; acc[0][1] += a0 * b1; acc[0][2] += a0 * b2; acc[0][3] += a0 * b3;
    acc[1][0] += a1 * b0; acc[1][1] += a1 * b1; acc[1][2] += a1 * b2; acc[1][3] += a1 * b3;
    acc[2][0] += a2 * b0; acc[2][1] += a2 * b1; acc[2][2] += a2 * b2; acc[2][3] += a2 * b3;
    acc[3][0] += a3 * b0; acc[3][1] += a3 * b1; acc[3][2] += a3 * b2; acc[3][3] += a3 * b3;
  }
}

// Per head: Wq = A*A*A2*A2, Wv = Av*Av — emitted as TRANSPOSED bf16 (WqT[j][i]).
__global__ __launch_bounds__(256) void k_weights(const float* __restrict__ WA, const float* __restrict__ WA2,
                                                 const float* __restrict__ WA3,
                                                 unsigned short* __restrict__ WqT,
                                                 unsigned short* __restrict__ WvT) {
  __shared__ float sA[64 * 65], sB[64 * 65], sT[64 * 65];
  const int h = blockIdx.x, t = threadIdx.x;
  const int tr = (t >> 4) * 4, tc = (t & 15) * 4;
  for (int i = t; i < 4096; i += 256) {
    int r = i >> 6, c = i & 63;
    sA[r * 65 + c] = WA[h * 4096 + i];
    sB[r * 65 + c] = WA2[h * 4096 + i];
  }
  __syncthreads();
  float acc[4][4];
  mm64(sA, sA, acc, tr, tc);           // T1 = A*A
#pragma unroll
  for (int rr = 0; rr < 4; ++rr)
#pragma unroll
    for (int cc = 0; cc < 4; ++cc) sT[(tr + rr) * 65 + tc + cc] = acc[rr][cc];
  __syncthreads();
  mm64(sT, sB, acc, tr, tc);           // T2 = T1*A2
#pragma unroll
  for (int rr = 0; rr < 4; ++rr)
#pragma unroll
    for (int cc = 0; cc < 4; ++cc) sA[(tr + rr) * 65 + tc + cc] = acc[rr][cc];
  __syncthreads();
  mm64(sA, sB, acc, tr, tc);           // Wq = T2*A2 -> transposed bf16
#pragma unroll
  for (int rr = 0; rr < 4; ++rr)
#pragma unroll
    for (int cc = 0; cc < 4; ++cc)
      WqT[h * 4096 + (tc + cc) * 64 + tr + rr] = f2bf(acc[rr][cc]);
  for (int i = t; i < 4096; i += 256) {
    int r = i >> 6, c = i & 63;
    sT[r * 65 + c] = WA3[h * 4096 + i];
  }
  __syncthreads();
  mm64(sT, sT, acc, tr, tc);           // Wv = Av*Av -> transposed bf16
#pragma unroll
  for (int rr = 0; rr < 4; ++rr)
#pragma unroll
    for (int cc = 0; cc < 4; ++cc)
      WvT[h * 4096 + (tc + cc) * 64 + tr + rr] = f2bf(acc[rr][cc]);
}

// f32 -> bf16 elementwise (vec4)
__global__ void k_conv(const float* __restrict__ s, unsigned short* __restrict__ d, int n4) {
  int i = blockIdx.x * blockDim.x + threadIdx.x;
  int stride = gridDim.x * blockDim.x;
  for (; i < n4; i += stride) {
    float4 f = ((const float4*)s)[i];
    ushort4 o;
    o.x = f2bf(f.x); o.y = f2bf(f.y); o.z = f2bf(f.z); o.w = f2bf(f.w);
    ((ushort4*)d)[i] = o;
  }
}

// mask int32 [b,row,key] -> bitmask u64 words [b*L+row][32]
__global__ __launch_bounds__(256) void k_maskpack(const int* __restrict__ mask,
                                                  unsigned long long* __restrict__ mp) {
  const int row = blockIdx.x * 4 + (threadIdx.x >> 6);
  const int lane = threadIdx.x & 63;
  const int* src = mask + (size_t)row * L_;
#pragma unroll
  for (int c = 0; c < 32; ++c) {
    int mv = src[c * 64 + lane];
    unsigned long long bits = __ballot(mv != 0);
    if (lane == 0) mp[(size_t)row * 32 + c] = bits;
  }
}

// load 8 consecutive f32 -> bf16x8 fragment
__device__ __forceinline__ bf16x8 ld_bf8(const float* p) {
  union { unsigned short u[8]; bf16x8 v; } t;
  float4 x0 = *(const float4*)p;
  float4 x1 = *(const float4*)(p + 4);
  t.u[0] = f2bf(x0.x); t.u[1] = f2bf(x0.y); t.u[2] = f2bf(x0.z); t.u[3] = f2bf(x0.w);
  t.u[4] = f2bf(x1.x); t.u[5] = f2bf(x1.y); t.u[6] = f2bf(x1.z); t.u[7] = f2bf(x1.w);
  return t.v;
}

// Q'[b,row,h*64+dk] = (q_head @ Wq[h]) * (1/8)*log2(e), bf16 — MFMA version.
__global__ __launch_bounds__(256) void k_qprime(const float* __restrict__ q,
                                                const unsigned short* __restrict__ WqT,
                                                unsigned short* __restrict__ Qp) {
  const int bid = blockIdx.x;
  const int rt = bid & 31, h = (bid >> 5) & 7, b = bid >> 8;
  const int tid = threadIdx.x, lane = tid & 63, w = tid >> 6;
  const int l15 = lane & 15, l4 = lane >> 4;
  const int row0 = rt * 64 + w * 16;
  const float QS = 0.125f * 1.44269504088896f;
  const float* qp = q + (size_t)(b * L_ + row0 + l15) * DM + h * DK + l4 * 8;
  bf16x8 a0 = ld_bf8(qp);
  bf16x8 a1 = ld_bf8(qp + 32);
  f32x4 acc[4];
#pragma unroll
  for (int cb = 0; cb < 4; ++cb) {
    const unsigned short* wp = WqT + h * 4096 + (cb * 16 + l15) * 64 + l4 * 8;
    bf16x8 b0 = *(const bf16x8*)wp;
    bf16x8 b1 = *(const bf16x8*)(wp + 32);
    f32x4 z = {0.f, 0.f, 0.f, 0.f};
    z = mfma16(a0, b0, z);
    acc[cb] = mfma16(a1, b1, z);
  }
#pragma unroll
  for (int cb = 0; cb < 4; ++cb)
#pragma unroll
    for (int r = 0; r < 4; ++r)
      Qp[(size_t)(b * L_ + row0 + l4 * 4 + r) * DM + h * DK + cb * 16 + l15] =
          f2bf(acc[cb][r] * QS);
}

// V'T[b,h,dk,key] = (v_head @ Wv[h])^T, bf16 — MFMA + per-wave LDS transpose.
__global__ __launch_bounds__(256) void k_vprime(const float* __restrict__ v,
                                                const unsigned short* __restrict__ WvT,
                                                unsigned short* __restrict__ VpT) {
  __shared__ __align__(16) unsigned short T[4][64 * 24];  // [wave][dk][key], stride 24
  const int bid = blockIdx.x;
  const int rt = bid & 31, h = (bid >> 5) & 7, b = bid >> 8;
  const int tid = threadIdx.x, lane = tid & 63, w = tid >> 6;
  const int l15 = lane & 15, l4 = lane >> 4;
  const int key0 = rt * 64 + w * 16;
  const float* vp = v + (size_t)(b * L_ + key0 + l15) * DM + h * DK + l4 * 8;
  bf16x8 a0 = ld_bf8(vp);
  bf16x8 a1 = ld_bf8(vp + 32);
  f32x4 acc[4];
#pragma unroll
  for (int cb = 0; cb < 4; ++cb) {
    const unsigned short* wp = WvT + h * 4096 + (cb * 16 + l15) * 64 + l4 * 8;
    bf16x8 b0 = *(const bf16x8*)wp;
    bf16x8 b1 = *(const bf16x8*)(wp + 32);
    f32x4 z = {0.f, 0.f, 0.f, 0.f};
    z = mfma16(a0, b0, z);
    acc[cb] = mfma16(a1, b1, z);
  }
  // acc[cb][r]: key-row = l4*4+r, dk-col = cb*16+l15 -> LDS [dk][key]
#pragma unroll
  for (int cb = 0; cb < 4; ++cb)
#pragma unroll
    for (int r = 0; r < 4; ++r)
      T[w][(cb * 16 + l15) * 24 + l4 * 4 + r] = f2bf(acc[cb][r]);
  __syncthreads();
  const unsigned short* src = &T[w][lane * 24];
  uint4 t0 = *(const uint4*)src;
  uint4 t1 = *(const uint4*)(src + 8);
  size_t go = ((size_t)((b * H_ + h) * DK + lane)) * L_ + key0;
  *(uint4*)&VpT[go] = t0;
  *(uint4*)&VpT[go + 8] = t1;
}

// Fused attention, swapped-operand S^T layout (R7 structure, proven 319.5us).
__global__ __launch_bounds__(256, 4) void k_attn(const unsigned short* __restrict__ Qp,
                                                 const unsigned short* __restrict__ Kb,
                                                 const unsigned short* __restrict__ VpT,
                                                 const unsigned long long* __restrict__ mp,
                                                 float* __restrict__ attn,
                                                 float* __restrict__ ov) {
  __shared__ __align__(16) unsigned short KT[2][4096];  // 64 keys x 64 dk, swizzled
  __shared__ __align__(16) unsigned short VT[2][4096];  // 64 dk x 64 keys, swizzled
  __shared__ __align__(16) unsigned short PB[4][1024];  // per-wave P, [16 qrows][64 keys] swz
  const int bid0 = blockIdx.x;
  const int bid = (bid0 & 7) * 128 + (bid0 >> 3);  // XCD swizzle (1024 % 8 == 0)
  const int qt = bid & 31;
  const int h = (bid >> 5) & 7;
  const int b = bid >> 8;
  const int tid = threadIdx.x;
  const int lane = tid & 63;
  const int w = tid >> 6;
  const int l15 = lane & 15, l4 = lane >> 4;
  const int row0 = qt * 64 + w * 16;

  const unsigned short* qb = Qp + ((size_t)(b * L_ + row0 + l15)) * DM + h * DK + l4 * 8;
  const bf16x8 aQ0 = *(const bf16x8*)qb;
  const bf16x8 aQ1 = *(const bf16x8*)(qb + 32);

  const size_t kb_base = (size_t)b * L_ * DM + h * DK;
  const size_t vt_base = (size_t)((b * H_ + h) * DK) * L_;
  const unsigned long long* mrowl = mp + (size_t)(b * L_ + row0 + l15) * 32;

  const int p_lo = tid * 16;
  const int skey = p_lo >> 7;
  const int sboff = (p_lo & 127) ^ ((skey & 7) << 4);
  const int skey1 = (p_lo + 4096) >> 7;
  const int sboff1 = ((p_lo + 4096) & 127) ^ ((skey1 & 7) << 4);

#define STAGE_K(kt_, s_)                                                                   \
  {                                                                                        \
    async16(Kb + kb_base + (size_t)((kt_) * 64 + skey) * DM + (sboff >> 1),                \
            (char*)&KT[s_][0] + p_lo);                                                     \
    async16(Kb + kb_base + (size_t)((kt_) * 64 + skey1) * DM + (sboff1 >> 1),              \
            (char*)&KT[s_][0] + p_lo + 4096);                                              \
  }
#define STAGE_V(kt_, s_)                                                                   \
  {                                                                                        \
    async16(VpT + vt_base + (size_t)skey * L_ + (kt_) * 64 + (sboff >> 1),                 \
            (char*)&VT[s_][0] + p_lo);                                                     \
    async16(VpT + vt_base + (size_t)skey1 * L_ + (kt_) * 64 + (sboff1 >> 1),               \
            (char*)&VT[s_][0] + p_lo + 4096);                                              \
  }

  float lsum = 0.f;
  unsigned long long mwA, mwB;

  // ================= Pass 1: denominators =================
  mwA = mrowl[0];
  mwB = mrowl[1];
  STAGE_K(0, 0);
  asm volatile("s_waitcnt vmcnt(0)" ::: "memory");
  __builtin_amdgcn_s_barrier();

#define P1_BODY(KT_, VMN_, DO_STAGE_, DO_LOADM_)                                           \
  {                                                                                        \
    const int kt = (KT_);                                                                  \
    const int cur = kt & 1;                                                                \
    __builtin_amdgcn_sched_barrier(0);                                                     \
    unsigned long long mwN = 0ull;                                                         \
    if (DO_LOADM_) mwN = mrowl[kt + 2];                                                    \
    if (DO_STAGE_) STAGE_K(kt + 1, cur ^ 1);                                               \
    asm volatile("s_waitcnt vmcnt(" #VMN_ ")" ::: "memory");                               \
    __builtin_amdgcn_sched_barrier(0);                                                     \
    __builtin_amdgcn_s_barrier();                                                          \
    const char* Kbase = (const char*)&KT[cur][0];                                          \
    _Pragma("unroll") for (int f = 0; f < 4; ++f) {                                        \
      int keyrow = f * 16 + l15;                                                           \
      int sw = (keyrow & 7) << 4;                                                          \
      bf16x8 b0 = *(const bf16x8*)(Kbase + keyrow * 128 + ((l4 * 16) ^ sw));               \
      bf16x8 b1 = *(const bf16x8*)(Kbase + keyrow * 128 + ((64 + l4 * 16) ^ sw));          \
      f32x4 acc = {0.f, 0.f, 0.f, 0.f};                                                    \
      acc = mfma16(b0, aQ0, acc);                                                          \
      acc = mfma16(b1, aQ1, acc);                                                          \
      unsigned nib = (unsigned)(mwA >> (f * 16 + l4 * 4));                                 \
      _Pragma("unroll") for (int r = 0; r < 4; ++r)                                        \
        lsum += ((nib >> r) & 1u) ? fexp2(acc[r]) : 0.f;                                   \
    }                                                                                      \
    __builtin_amdgcn_s_barrier();                                                          \
    mwA = mwB; mwB = mwN;                                                                  \
  }

  for (int t = 0; t < 30; ++t) P1_BODY(t, 3, true, true);
  P1_BODY(30, 2, true, false);
  P1_BODY(31, 0, false, false);
#undef P1_BODY

  lsum += __shfl_xor(lsum, 16);
  lsum += __shfl_xor(lsum, 32);
  const float invl = 1.0f / lsum;

  f32x4 O[4];
#pragma unroll
  for (int d = 0; d < 4; ++d) { f32x4 z = {0.f, 0.f, 0.f, 0.f}; O[d] = z; }

  float* arowl = attn + ((size_t)((b * H_ + h) * L_) + row0 + l15) * L_;
  char* pbw = (char*)&PB[w][0];
  const int psw = (l15 & 7) << 4;

  // ================= Pass 2: P write + PV =================
  mwA = mrowl[0];
  mwB = mrowl[1];
  STAGE_K(0, 0);
  STAGE_V(0, 0);
  asm volatile("s_waitcnt vmcnt(0)" ::: "memory");
  __builtin_amdgcn_s_barrier();

#define P2_BODY(KT_, VMN_, DO_STAGE_, DO_LOADM_)                                           \
  {                                                                                        \
    const int kt = (KT_);                                                                  \
    const int cur = kt & 1;                                                                \
    const int key0 = kt * 64;                                                              \
    __builtin_amdgcn_sched_barrier(0);                                                     \
    unsigned long long mwN = 0ull;                                                         \
    if (DO_LOADM_) mwN = mrowl[kt + 2];                                                    \
    if (DO_STAGE_) { STAGE_K(kt + 1, cur ^ 1); STAGE_V(kt + 1, cur ^ 1); }                 \
    asm volatile("s_waitcnt vmcnt(" #VMN_ ")" ::: "memory");                               \
    __builtin_amdgcn_sched_barrier(0);                                                     \
    __builtin_amdgcn_s_barrier();                                                          \
    const char* Kbase = (const char*)&KT[cur][0];                                          \
    const char* Vbase = (const char*)&VT[cur][0];                                          \
    float pvv[4][4];                                                                       \
    _Pragma("unroll") for (int f = 0; f < 4; ++f) {                                        \
      int keyrow = f * 16 + l15;                                                           \
      int sw = (keyrow & 7) << 4;                                                          \
      bf16x8 b0 = *(const bf16x8*)(Kbase + keyrow * 128 + ((l4 * 16) ^ sw));               \
      bf16x8 b1 = *(const bf16x8*)(Kbase + keyrow * 128 + ((64 + l4 * 16) ^ sw));          \
      f32x4 acc = {0.f, 0.f, 0.f, 0.f};                                                    \
      acc = mfma16(b0, aQ0, acc);                                                          \
      acc = mfma16(b1, aQ1, acc);                                                          \
      unsigned nib = (unsigned)(mwA >> (f * 16 + l4 * 4));                                 \
      _Pragma("unroll") for (int r = 0; r < 4; ++r)                                        \
        pvv[f][r] = ((nib >> r) & 1u) ? fexp2(acc[r]) * invl : 0.f;                        \
    }                                                                                      \
    _Pragma("unroll") for (int f = 0; f < 4; ++f) {                                        \
      f32x4 sv;                                                                            \
      sv[0] = pvv[f][0]; sv[1] = pvv[f][1]; sv[2] = pvv[f][2]; sv[3] = pvv[f][3];          \
      __builtin_nontemporal_store(sv, (f32x4*)(arowl + key0 + f * 16 + l4 * 4));           \
    }                                                                                      \
    _Pragma("unroll") for (int f = 0; f < 4; ++f) {                                        \
      ushort4 pk;                                                                          \
      pk.x = f2bf(pvv[f][0]); pk.y = f2bf(pvv[f][1]);                                      \
      pk.z = f2bf(pvv[f][2]); pk.w = f2bf(pvv[f][3]);                                      \
      *(ushort4*)(pbw + l15 * 128 + ((f * 32 + l4 * 8) ^ psw)) = pk;                       \
    }                                                                                      \
    bf16x8 aP0 = *(const bf16x8*)(pbw + l15 * 128 + ((l4 * 16) ^ psw));                    \
    bf16x8 aP1 = *(const bf16x8*)(pbw + l15 * 128 + ((64 + l4 * 16) ^ psw));               \
    __builtin_amdgcn_s_setprio(1);                                                         \
    _Pragma("unroll") for (int d = 0; d < 4; ++d) {                                        \
      int dkrow = d * 16 + l15;                                                            \
      int sw = (dkrow & 7) << 4;                                                           \
      bf16x8 v0 = *(const bf16x8*)(Vbase + dkrow * 128 + ((l4 * 16) ^ sw));                \
      bf16x8 v1 = *(const bf16x8*)(Vbase + dkrow * 128 + ((64 + l4 * 16) ^ sw));           \
      O[d] = mfma16(aP0, v0, O[d]);                                                        \
      O[d] = mfma16(aP1, v1, O[d]);                                                        \
    }                                                                                      \
    __builtin_amdgcn_s_setprio(0);                                                         \
    __builtin_amdgcn_s_barrier();                                                          \
    mwA = mwB; mwB = mwN;                                                                  \
  }

  for (int t = 0; t < 30; ++t) P2_BODY(t, 9, true, true);
  P2_BODY(30, 8, true, false);
  P2_BODY(31, 4, false, false);
#undef P2_BODY

#pragma unroll
  for (int d = 0; d < 4; ++d)
#pragma unroll
    for (int r = 0; r < 4; ++r)
      ov[(size_t)(b * L_ + row0 + l4 * 4 + r) * DM + h * DK + d * 16 + l15] = O[d][r];
#undef STAGE_K
#undef STAGE_V
}

// out = LN(O @ fc^T + q) in place on d_out rows. Block = 16 token rows, wave = 128 cols.
__global__ __launch_bounds__(256) void k_proj(const float* __restrict__ qres,
                                              const unsigned short* __restrict__ fcb,
                                              const float* __restrict__ gamma,
                                              const float* __restrict__ beta,
                                              float* __restrict__ io) {
  __shared__ float red1[16][4], red2[16][4];
  const int blk = blockIdx.x;
  const int tid = threadIdx.x, lane = tid & 63, w = tid >> 6;
  const int l15 = lane & 15, l4 = lane >> 4;
  const int row0 = blk * 16;
  const float* arow = io + (size_t)(row0 + l15) * DM + l4 * 8;
  const unsigned short* bb = fcb + (size_t)(w * 128 + l15) * DM + l4 * 8;
  f32x4 C[8];
#pragma unroll
  for (int i = 0; i < 8; ++i) { f32x4 z = {0.f, 0.f, 0.f, 0.f}; C[i] = z; }
  for (int kc = 0; kc < 16; ++kc) {
    float4 a0 = *(const float4*)(arow + kc * 32);
    float4 a1 = *(const float4*)(arow + kc * 32 + 4);
    union { unsigned short u[8]; bf16x8 v; } t;
    t.u[0] = f2bf(a0.x); t.u[1] = f2bf(a0.y); t.u[2] = f2bf(a0.z); t.u[3] = f2bf(a0.w);
    t.u[4] = f2bf(a1.x); t.u[5] = f2bf(a1.y); t.u[6] = f2bf(a1.z); t.u[7] = f2bf(a1.w);
#pragma unroll
    for (int cf = 0; cf < 8; ++cf) {
      bf16x8 bv = *(const bf16x8*)(bb + (size_t)(cf * 16) * DM + kc * 32);
      C[cf] = mfma16(t.v, bv, C[cf]);
    }
  }
  float s1[4] = {0.f, 0.f, 0.f, 0.f}, s2[4] = {0.f, 0.f, 0.f, 0.f};
  const int colb = w * 128;
#pragma unroll
  for (int cf = 0; cf < 8; ++cf)
#pragma unroll
    for (int r = 0; r < 4; ++r) {
      float val = C[cf][r] + qres[(size_t)(row0 + l4 * 4 + r) * DM + colb + cf * 16 + l15];
      C[cf][r] = val;
      s1[r] += val;
      s2[r] += val * val;
    }
#pragma unroll
  for (int r = 0; r < 4; ++r) { s1[r] = rsum16(s1[r]); s2[r] = rsum16(s2[r]); }
  if (l15 == 0) {
#pragma unroll
    for (int r = 0; r < 4; ++r) { red1[l4 * 4 + r][w] = s1[r]; red2[l4 * 4 + r][w] = s2[r]; }
  }
  __syncthreads();
  float mu[4], rs[4];
#pragma unroll
  for (int r = 0; r < 4; ++r) {
    int row = l4 * 4 + r;
    float t1 = red1[row][0] + red1[row][1] + red1[row][2] + red1[row][3];
    float t2 = red2[row][0] + red2[row][1] + red2[row][2] + red2[row][3];
    float m_ = t1 * (1.0f / 512.0f);
    float var = t2 * (1.0f / 512.0f) - m_ * m_;
    mu[r] = m_;
    rs[r] = rsqrtf(var + 1e-6f);
  }
#pragma unroll
  for (int cf = 0; cf < 8; ++cf) {
    float g = gamma[colb + cf * 16 + l15];
    float be = beta[colb + cf * 16 + l15];
#pragma unroll
    for (int r = 0; r < 4; ++r)
      io[(size_t)(row0 + l4 * 4 + r) * DM + colb + cf * 16 + l15] =
          (C[cf][r] - mu[r]) * rs[r] * g + be;
  }
}

extern "C" void kernel_launch(void* const* d_in, const int* in_sizes, int n_in,
                              void* d_out, int out_size, void* d_ws, size_t ws_size,
                              hipStream_t stream) {
  (void)in_sizes; (void)n_in; (void)out_size; (void)ws_size;
  const float* q   = (const float*)d_in[0];
  const float* k   = (const float*)d_in[1];
  const float* v   = (const float*)d_in[2];
  const int* mask  = (const int*)d_in[3];
  const float* WA  = (const float*)d_in[4];
  const float* WA2 = (const float*)d_in[5];
  const float* WA3 = (const float*)d_in[6];
  const float* fcw = (const float*)d_in[7];
  const float* gam = (const float*)d_in[8];
  const float* bet = (const float*)d_in[9];
  float* out = (float*)d_out;
  float* attn = out + (size_t)B_ * L_ * DM;

  char* ws = (char*)d_ws;
  unsigned short* WqT = (unsigned short*)ws;                                        // 64KB
  unsigned short* WvT = (unsigned short*)(ws + 65536);                              // 64KB
  unsigned short* Qp  = (unsigned short*)(ws + 131072);                             // 8MB
  unsigned short* Kb  = (unsigned short*)(ws + 131072 + 8388608);                   // 8MB
  unsigned short* VpT = (unsigned short*)(ws + 131072 + 2 * 8388608);               // 8MB
  unsigned short* FCb = (unsigned short*)(ws + 131072 + 3 * 8388608);               // 512KB
  unsigned long long* mp = (unsigned long long*)(ws + 131072 + 3 * 8388608 + 524288);  // 2MB

  k_weights<<<8, 256, 0, stream>>>(WA, WA2, WA3, WqT, WvT);
  k_conv<<<1024, 256, 0, stream>>>(k, Kb, (B_ * L_ * DM) / 4);
  k_conv<<<256, 256, 0, stream>>>(fcw, FCb, (DM * DM) / 4);
  k_maskpack<<<2048, 256, 0, stream>>>(mask, mp);
  k_qprime<<<1024, 256, 0, stream>>>(q, WqT, Qp);
  k_vprime<<<1024, 256, 0, stream>>>(v, WvT, VpT);
  k_attn<<<1024, 256, 0, stream>>>(Qp, Kb, VpT, mp, attn, out);
  k_proj<<<512, 256, 0, stream>>>(q, FCb, gam, bet, out);
}

// Round 12
// 298.978 us; speedup vs baseline: 1.1883x; 1.0022x over previous
//
#include <hip/hip_runtime.h>

#define B_ 4
#define H_ 8
#define L_ 2048
#define DM 512
#define DK 64

typedef __bf16 bf16x8 __attribute__((ext_vector_type(8)));
typedef float f32x4 __attribute__((ext_vector_type(4)));

__device__ __forceinline__ f32x4 mfma16(bf16x8 a, bf16x8 b, f32x4 c) {
  return __builtin_amdgcn_mfma_f32_16x16x32_bf16(a, b, c, 0, 0, 0);
}
__device__ __forceinline__ unsigned short f2bf(float f) {
  unsigned int u = __float_as_uint(f);
  u += 0x7fffu + ((u >> 16) & 1u);
  return (unsigned short)(u >> 16);
}
__device__ __forceinline__ float fexp2(float x) {
  float r;
  asm("v_exp_f32 %0, %1" : "=v"(r) : "v"(x));
  return r;
}
__device__ __forceinline__ void async16(const void* g, void* l) {
  __builtin_amdgcn_global_load_lds((const __attribute__((address_space(1))) unsigned int*)g,
                                   (__attribute__((address_space(3))) unsigned int*)l, 16, 0, 0);
}
__device__ __forceinline__ float rsum16(float v) {
  v += __shfl_xor(v, 1);
  v += __shfl_xor(v, 2);
  v += __shfl_xor(v, 4);
  v += __shfl_xor(v, 8);
  return v;
}

// D = X(64x64, stride 65) @ Y(64x64, stride 65); thread computes 4x4 tile.
__device__ __forceinline__ void mm64(const float* X, const float* Y, float acc[4][4], int tr, int tc) {
#pragma unroll
  for (int rr = 0; rr < 4; ++rr)
#pragma unroll
    for (int cc = 0; cc < 4; ++cc) acc[rr][cc] = 0.f;
  for (int c = 0; c < 64; ++c) {
    float a0 = X[(tr + 0) * 65 + c], a1 = X[(tr + 1) * 65 + c];
    float a2 = X[(tr + 2) * 65 + c], a3 = X[(tr + 3) * 65 + c];
    float b0 = Y[c * 65 + tc + 0], b1 = Y[c * 65 + tc + 1];
    float b2 = Y[c * 65 + tc + 2], b3 = Y[c * 65 + tc + 3];
    acc[0][0] += a0 * b0; acc[0][1] += a0 * b1; acc[0][2] += a0 * b2; acc[0][3] += a0 * b3;
    acc[1][0] += a1 * b0; acc[1][1] += a1 * b1; acc[1][2] += a1 * b2; acc[1][3] += a1 * b3;
    acc[2][0] += a2 * b0; acc[2][1] += a2 * b1; acc[2][2] += a2 * b2; acc[2][3] += a2 * b3;
    acc[3][0] += a3 * b0; acc[3][1] += a3 * b1; acc[3][2] += a3 * b2; acc[3][3] += a3 * b3;
  }
}

// Per head: Wq = A*A*A2*A2, Wv = Av*Av — emitted as TRANSPOSED bf16 (WqT[j][i]).
__global__ __launch_bounds__(256) void k_weights(const float* __restrict__ WA, const float* __restrict__ WA2,
                                                 const float* __restrict__ WA3,
                                                 unsigned short* __restrict__ WqT,
                                                 unsigned short* __restrict__ WvT) {
  __shared__ float sA[64 * 65], sB[64 * 65], sT[64 * 65];
  const int h = blockIdx.x, t = threadIdx.x;
  const int tr = (t >> 4) * 4, tc = (t & 15) * 4;
  for (int i = t; i < 4096; i += 256) {
    int r = i >> 6, c = i & 63;
    sA[r * 65 + c] = WA[h * 4096 + i];
    sB[r * 65 + c] = WA2[h * 4096 + i];
  }
  __syncthreads();
  float acc[4][4];
  mm64(sA, sA, acc, tr, tc);           // T1 = A*A
#pragma unroll
  for (int rr = 0; rr < 4; ++rr)
#pragma unroll
    for (int cc = 0; cc < 4; ++cc) sT[(tr + rr) * 65 + tc + cc] = acc[rr][cc];
  __syncthreads();
  mm64(sT, sB, acc, tr, tc);           // T2 = T1*A2
#pragma unroll
  for (int rr = 0; rr < 4; ++rr)
#pragma unroll
    for (int cc = 0; cc < 4; ++cc) sA[(tr + rr) * 65 + tc + cc] = acc[rr][cc];
  __syncthreads();
  mm64(sA, sB, acc, tr, tc);           // Wq = T2*A2 -> transposed bf16
#pragma unroll
  for (int rr = 0; rr < 4; ++rr)
#pragma unroll
    for (int cc = 0; cc < 4; ++cc)
      WqT[h * 4096 + (tc + cc) * 64 + tr + rr] = f2bf(acc[rr][cc]);
  for (int i = t; i < 4096; i += 256) {
    int r = i >> 6, c = i & 63;
    sT[r * 65 + c] = WA3[h * 4096 + i];
  }
  __syncthreads();
  mm64(sT, sT, acc, tr, tc);           // Wv = Av*Av -> transposed bf16
#pragma unroll
  for (int rr = 0; rr < 4; ++rr)
#pragma unroll
    for (int cc = 0; cc < 4; ++cc)
      WvT[h * 4096 + (tc + cc) * 64 + tr + rr] = f2bf(acc[rr][cc]);
}

// f32 -> bf16 elementwise (vec4)
__global__ void k_conv(const float* __restrict__ s, unsigned short* __restrict__ d, int n4) {
  int i = blockIdx.x * blockDim.x + threadIdx.x;
  int stride = gridDim.x * blockDim.x;
  for (; i < n4; i += stride) {
    float4 f = ((const float4*)s)[i];
    ushort4 o;
    o.x = f2bf(f.x); o.y = f2bf(f.y); o.z = f2bf(f.z); o.w = f2bf(f.w);
    ((ushort4*)d)[i] = o;
  }
}

// mask int32 [b,row,key] -> bitmask u64 words [b*L+row][32]
__global__ __launch_bounds__(256) void k_maskpack(const int* __restrict__ mask,
                                                  unsigned long long* __restrict__ mp) {
  const int row = blockIdx.x * 4 + (threadIdx.x >> 6);
  const int lane = threadIdx.x & 63;
  const int* src = mask + (size_t)row * L_;
#pragma unroll
  for (int c = 0; c < 32; ++c) {
    int mv = src[c * 64 + lane];
    unsigned long long bits = __ballot(mv != 0);
    if (lane == 0) mp[(size_t)row * 32 + c] = bits;
  }
}

// load 8 consecutive f32 -> bf16x8 fragment
__device__ __forceinline__ bf16x8 ld_bf8(const float* p) {
  union { unsigned short u[8]; bf16x8 v; } t;
  float4 x0 = *(const float4*)p;
  float4 x1 = *(const float4*)(p + 4);
  t.u[0] = f2bf(x0.x); t.u[1] = f2bf(x0.y); t.u[2] = f2bf(x0.z); t.u[3] = f2bf(x0.w);
  t.u[4] = f2bf(x1.x); t.u[5] = f2bf(x1.y); t.u[6] = f2bf(x1.z); t.u[7] = f2bf(x1.w);
  return t.v;
}

// Q'[b,row,h*64+dk] = (q_head @ Wq[h]) * (1/8)*log2(e), bf16 — MFMA version.
__global__ __launch_bounds__(256) void k_qprime(const float* __restrict__ q,
                                                const unsigned short* __restrict__ WqT,
                                                unsigned short* __restrict__ Qp) {
  const int bid = blockIdx.x;
  const int rt = bid & 31, h = (bid >> 5) & 7, b = bid >> 8;
  const int tid = threadIdx.x, lane = tid & 63, w = tid >> 6;
  const int l15 = lane & 15, l4 = lane >> 4;
  const int row0 = rt * 64 + w * 16;
  const float QS = 0.125f * 1.44269504088896f;
  const float* qp = q + (size_t)(b * L_ + row0 + l15) * DM + h * DK + l4 * 8;
  bf16x8 a0 = ld_bf8(qp);
  bf16x8 a1 = ld_bf8(qp + 32);
  f32x4 acc[4];
#pragma unroll
  for (int cb = 0; cb < 4; ++cb) {
    const unsigned short* wp = WqT + h * 4096 + (cb * 16 + l15) * 64 + l4 * 8;
    bf16x8 b0 = *(const bf16x8*)wp;
    bf16x8 b1 = *(const bf16x8*)(wp + 32);
    f32x4 z = {0.f, 0.f, 0.f, 0.f};
    z = mfma16(a0, b0, z);
    acc[cb] = mfma16(a1, b1, z);
  }
#pragma unroll
  for (int cb = 0; cb < 4; ++cb)
#pragma unroll
    for (int r = 0; r < 4; ++r)
      Qp[(size_t)(b * L_ + row0 + l4 * 4 + r) * DM + h * DK + cb * 16 + l15] =
          f2bf(acc[cb][r] * QS);
}

// V'T[b,h,dk,key] = (v_head @ Wv[h])^T, bf16 — MFMA + per-wave LDS transpose.
__global__ __launch_bounds__(256) void k_vprime(const float* __restrict__ v,
                                                const unsigned short* __restrict__ WvT,
                                                unsigned short* __restrict__ VpT) {
  __shared__ __align__(16) unsigned short T[4][64 * 24];  // [wave][dk][key], stride 24
  const int bid = blockIdx.x;
  const int rt = bid & 31, h = (bid >> 5) & 7, b = bid >> 8;
  const int tid = threadIdx.x, lane = tid & 63, w = tid >> 6;
  const int l15 = lane & 15, l4 = lane >> 4;
  const int key0 = rt * 64 + w * 16;
  const float* vp = v + (size_t)(b * L_ + key0 + l15) * DM + h * DK + l4 * 8;
  bf16x8 a0 = ld_bf8(vp);
  bf16x8 a1 = ld_bf8(vp + 32);
  f32x4 acc[4];
#pragma unroll
  for (int cb = 0; cb < 4; ++cb) {
    const unsigned short* wp = WvT + h * 4096 + (cb * 16 + l15) * 64 + l4 * 8;
    bf16x8 b0 = *(const bf16x8*)wp;
    bf16x8 b1 = *(const bf16x8*)(wp + 32);
    f32x4 z = {0.f, 0.f, 0.f, 0.f};
    z = mfma16(a0, b0, z);
    acc[cb] = mfma16(a1, b1, z);
  }
  // acc[cb][r]: key-row = l4*4+r, dk-col = cb*16+l15 -> LDS [dk][key]
#pragma unroll
  for (int cb = 0; cb < 4; ++cb)
#pragma unroll
    for (int r = 0; r < 4; ++r)
      T[w][(cb * 16 + l15) * 24 + l4 * 4 + r] = f2bf(acc[cb][r]);
  __syncthreads();
  const unsigned short* src = &T[w][lane * 24];
  uint4 t0 = *(const uint4*)src;
  uint4 t1 = *(const uint4*)(src + 8);
  size_t go = ((size_t)((b * H_ + h) * DK + lane)) * L_ + key0;
  *(uint4*)&VpT[go] = t0;
  *(uint4*)&VpT[go + 8] = t1;
}

// Fused attention, swapped-operand S^T layout. Canonical 1-barrier-per-tile
// 2-phase loops: stage(t+1) -> compute(t) -> counted vmcnt (stage only; stores
// never drain on the critical path) -> single barrier.
__global__ __launch_bounds__(256, 4) void k_attn(const unsigned short* __restrict__ Qp,
                                                 const unsigned short* __restrict__ Kb,
                                                 const unsigned short* __restrict__ VpT,
                                                 const unsigned long long* __restrict__ mp,
                                                 float* __restrict__ attn,
                                                 float* __restrict__ ov) {
  __shared__ __align__(16) unsigned short KT[2][4096];  // 64 keys x 64 dk, swizzled
  __shared__ __align__(16) unsigned short VT[2][4096];  // 64 dk x 64 keys, swizzled
  __shared__ __align__(16) unsigned short PB[4][1024];  // per-wave P, [16 qrows][64 keys] swz
  const int bid0 = blockIdx.x;
  const int bid = (bid0 & 7) * 128 + (bid0 >> 3);  // XCD swizzle (1024 % 8 == 0)
  const int qt = bid & 31;
  const int h = (bid >> 5) & 7;
  const int b = bid >> 8;
  const int tid = threadIdx.x;
  const int lane = tid & 63;
  const int w = tid >> 6;
  const int l15 = lane & 15, l4 = lane >> 4;
  const int row0 = qt * 64 + w * 16;

  const unsigned short* qb = Qp + ((size_t)(b * L_ + row0 + l15)) * DM + h * DK + l4 * 8;
  const bf16x8 aQ0 = *(const bf16x8*)qb;
  const bf16x8 aQ1 = *(const bf16x8*)(qb + 32);

  const size_t kb_base = (size_t)b * L_ * DM + h * DK;
  const size_t vt_base = (size_t)((b * H_ + h) * DK) * L_;
  const unsigned long long* mrowl = mp + (size_t)(b * L_ + row0 + l15) * 32;

  const int p_lo = tid * 16;
  const int skey = p_lo >> 7;
  const int sboff = (p_lo & 127) ^ ((skey & 7) << 4);
  const int skey1 = (p_lo + 4096) >> 7;
  const int sboff1 = ((p_lo + 4096) & 127) ^ ((skey1 & 7) << 4);

#define STAGE_K(kt_, s_)                                                                   \
  {                                                                                        \
    async16(Kb + kb_base + (size_t)((kt_) * 64 + skey) * DM + (sboff >> 1),                \
            (char*)&KT[s_][0] + p_lo);                                                     \
    async16(Kb + kb_base + (size_t)((kt_) * 64 + skey1) * DM + (sboff1 >> 1),              \
            (char*)&KT[s_][0] + p_lo + 4096);                                              \
  }
#define STAGE_V(kt_, s_)                                                                   \
  {                                                                                        \
    async16(VpT + vt_base + (size_t)skey * L_ + (kt_) * 64 + (sboff >> 1),                 \
            (char*)&VT[s_][0] + p_lo);                                                     \
    async16(VpT + vt_base + (size_t)skey1 * L_ + (kt_) * 64 + (sboff1 >> 1),               \
            (char*)&VT[s_][0] + p_lo + 4096);                                              \
  }

  float lsum = 0.f;
  unsigned long long mwA, mwB;

  // ================= Pass 1: denominators =================
  mwA = mrowl[0];
  mwB = mrowl[1];
  STAGE_K(0, 0);
  asm volatile("s_waitcnt vmcnt(0)" ::: "memory");
  __builtin_amdgcn_s_barrier();

#define P1_BODY(KT_, DO_STAGE_, DO_LOADM_, DO_BAR_)                                        \
  {                                                                                        \
    const int kt = (KT_);                                                                  \
    const int cur = kt & 1;                                                                \
    unsigned long long mwN = 0ull;                                                         \
    if (DO_LOADM_) mwN = mrowl[kt + 2];                                                    \
    if (DO_STAGE_) STAGE_K(kt + 1, cur ^ 1);                                               \
    __builtin_amdgcn_sched_barrier(0);                                                     \
    const char* Kbase = (const char*)&KT[cur][0];                                          \
    _Pragma("unroll") for (int f = 0; f < 4; ++f) {                                        \
      int keyrow = f * 16 + l15;                                                           \
      int sw = (keyrow & 7) << 4;                                                          \
      bf16x8 b0 = *(const bf16x8*)(Kbase + keyrow * 128 + ((l4 * 16) ^ sw));               \
      bf16x8 b1 = *(const bf16x8*)(Kbase + keyrow * 128 + ((64 + l4 * 16) ^ sw));          \
      f32x4 acc = {0.f, 0.f, 0.f, 0.f};                                                    \
      acc = mfma16(b0, aQ0, acc);                                                          \
      acc = mfma16(b1, aQ1, acc);                                                          \
      unsigned nib = (unsigned)(mwA >> (f * 16 + l4 * 4));                                 \
      _Pragma("unroll") for (int r = 0; r < 4; ++r)                                        \
        lsum += ((nib >> r) & 1u) ? fexp2(acc[r]) : 0.f;                                   \
    }                                                                                      \
    if (DO_BAR_) {                                                                         \
      asm volatile("s_waitcnt vmcnt(0)" ::: "memory");                                     \
      __builtin_amdgcn_sched_barrier(0);                                                   \
      __builtin_amdgcn_s_barrier();                                                        \
    }                                                                                      \
    mwA = mwB; mwB = mwN;                                                                  \
  }

  for (int t = 0; t < 30; ++t) P1_BODY(t, true, true, true);
  P1_BODY(30, true, false, true);
  P1_BODY(31, false, false, false);
#undef P1_BODY

  lsum += __shfl_xor(lsum, 16);
  lsum += __shfl_xor(lsum, 32);
  const float invl = 1.0f / lsum;

  f32x4 O[4];
#pragma unroll
  for (int d = 0; d < 4; ++d) { f32x4 z = {0.f, 0.f, 0.f, 0.f}; O[d] = z; }

  float* arowl = attn + ((size_t)((b * H_ + h) * L_) + row0 + l15) * L_;
  char* pbw = (char*)&PB[w][0];
  const int psw = (l15 & 7) << 4;

  // ================= Pass 2: P write + PV =================
  mwA = mrowl[0];
  mwB = mrowl[1];
  STAGE_K(0, 0);
  STAGE_V(0, 0);
  asm volatile("s_waitcnt vmcnt(0)" ::: "memory");
  __builtin_amdgcn_s_barrier();

#define P2_BODY(KT_, DO_STAGE_, DO_LOADM_, DO_BAR_)                                        \
  {                                                                                        \
    const int kt = (KT_);                                                                  \
    const int cur = kt & 1;                                                                \
    const int key0 = kt * 64;                                                              \
    unsigned long long mwN = 0ull;                                                         \
    if (DO_LOADM_) mwN = mrowl[kt + 2];                                                    \
    if (DO_STAGE_) { STAGE_K(kt + 1, cur ^ 1); STAGE_V(kt + 1, cur ^ 1); }                 \
    __builtin_amdgcn_sched_barrier(0);                                                     \
    const char* Kbase = (const char*)&KT[cur][0];                                          \
    const char* Vbase = (const char*)&VT[cur][0];                                          \
    float pvv[4][4];                                                                       \
    _Pragma("unroll") for (int f = 0; f < 4; ++f) {                                        \
      int keyrow = f * 16 + l15;                                                           \
      int sw = (keyrow & 7) << 4;                                                          \
      bf16x8 b0 = *(const bf16x8*)(Kbase + keyrow * 128 + ((l4 * 16) ^ sw));               \
      bf16x8 b1 = *(const bf16x8*)(Kbase + keyrow * 128 + ((64 + l4 * 16) ^ sw));          \
      f32x4 acc = {0.f, 0.f, 0.f, 0.f};                                                    \
      acc = mfma16(b0, aQ0, acc);                                                          \
      acc = mfma16(b1, aQ1, acc);                                                          \
      unsigned nib = (unsigned)(mwA >> (f * 16 + l4 * 4));                                 \
      _Pragma("unroll") for (int r = 0; r < 4; ++r)                                        \
        pvv[f][r] = ((nib >> r) & 1u) ? fexp2(acc[r]) * invl : 0.f;                        \
    }                                                                                      \
    _Pragma("unroll") for (int f = 0; f < 4; ++f) {                                        \
      f32x4 sv;                                                                            \
      sv[0] = pvv[f][0]; sv[1] = pvv[f][1]; sv[2] = pvv[f][2]; sv[3] = pvv[f][3];          \
      __builtin_nontemporal_store(sv, (f32x4*)(arowl + key0 + f * 16 + l4 * 4));           \
    }                                                                                      \
    _Pragma("unroll") for (int f = 0; f < 4; ++f) {                                        \
      ushort4 pk;                                                                          \
      pk.x = f2bf(pvv[f][0]); pk.y = f2bf(pvv[f][1]);                                      \
      pk.z = f2bf(pvv[f][2]); pk.w = f2bf(pvv[f][3]);                                      \
      *(ushort4*)(pbw + l15 * 128 + ((f * 32 + l4 * 8) ^ psw)) = pk;                       \
    }                                                                                      \
    bf16x8 aP0 = *(const bf16x8*)(pbw + l15 * 128 + ((l4 * 16) ^ psw));                    \
    bf16x8 aP1 = *(const bf16x8*)(pbw + l15 * 128 + ((64 + l4 * 16) ^ psw));               \
    __builtin_amdgcn_s_setprio(1);                                                         \
    _Pragma("unroll") for (int d = 0; d < 4; ++d) {                                        \
      int dkrow = d * 16 + l15;                                                            \
      int sw = (dkrow & 7) << 4;                                                           \
      bf16x8 v0 = *(const bf16x8*)(Vbase + dkrow * 128 + ((l4 * 16) ^ sw));                \
      bf16x8 v1 = *(const bf16x8*)(Vbase + dkrow * 128 + ((64 + l4 * 16) ^ sw));           \
      O[d] = mfma16(aP0, v0, O[d]);                                                        \
      O[d] = mfma16(aP1, v1, O[d]);                                                        \
    }                                                                                      \
    __builtin_amdgcn_s_setprio(0);                                                         \
    if (DO_BAR_) {                                                                         \
      asm volatile("s_waitcnt vmcnt(16)" ::: "memory");                                    \
      __builtin_amdgcn_sched_barrier(0);                                                   \
      __builtin_amdgcn_s_barrier();                                                        \
    }                                                                                      \
    mwA = mwB; mwB = mwN;                                                                  \
  }

  for (int t = 0; t < 30; ++t) P2_BODY(t, true, true, true);
  P2_BODY(30, true, false, true);
  P2_BODY(31, false, false, false);
#undef P2_BODY

#pragma unroll
  for (int d = 0; d < 4; ++d)
#pragma unroll
    for (int r = 0; r < 4; ++r)
      ov[(size_t)(b * L_ + row0 + l4 * 4 + r) * DM + h * DK + d * 16 + l15] = O[d][r];
#undef STAGE_K
#undef STAGE_V
}

// out = LN(O @ fc^T + q) in place on d_out rows. Block = 16 token rows, wave = 128 cols.
__global__ __launch_bounds__(256) void k_proj(const float* __restrict__ qres,
                                              const unsigned short* __restrict__ fcb,
                                              const float* __restrict__ gamma,
                                              const float* __restrict__ beta,
                                              float* __restrict__ io) {
  __shared__ float red1[16][4], red2[16][4];
  const int blk = blockIdx.x;
  const int tid = threadIdx.x, lane = tid & 63, w = tid >> 6;
  const int l15 = lane & 15, l4 = lane >> 4;
  const int row0 = blk * 16;
  const float* arow = io + (size_t)(row0 + l15) * DM + l4 * 8;
  const unsigned short* bb = fcb + (size_t)(w * 128 + l15) * DM + l4 * 8;
  f32x4 C[8];
#pragma unroll
  for (int i = 0; i < 8; ++i) { f32x4 z = {0.f, 0.f, 0.f, 0.f}; C[i] = z; }
  for (int kc = 0; kc < 16; ++kc) {
    float4 a0 = *(const float4*)(arow + kc * 32);
    float4 a1 = *(const float4*)(arow + kc * 32 + 4);
    union { unsigned short u[8]; bf16x8 v; } t;
    t.u[0] = f2bf(a0.x); t.u[1] = f2bf(a0.y); t.u[2] = f2bf(a0.z); t.u[3] = f2bf(a0.w);
    t.u[4] = f2bf(a1.x); t.u[5] = f2bf(a1.y); t.u[6] = f2bf(a1.z); t.u[7] = f2bf(a1.w);
#pragma unroll
    for (int cf = 0; cf < 8; ++cf) {
      bf16x8 bv = *(const bf16x8*)(bb + (size_t)(cf * 16) * DM + kc * 32);
      C[cf] = mfma16(t.v, bv, C[cf]);
    }
  }
  float s1[4] = {0.f, 0.f, 0.f, 0.f}, s2[4] = {0.f, 0.f, 0.f, 0.f};
  const int colb = w * 128;
#pragma unroll
  for (int cf = 0; cf < 8; ++cf)
#pragma unroll
    for (int r = 0; r < 4; ++r) {
      float val = C[cf][r] + qres[(size_t)(row0 + l4 * 4 + r) * DM + colb + cf * 16 + l15];
      C[cf][r] = val;
      s1[r] += val;
      s2[r] += val * val;
    }
#pragma unroll
  for (int r = 0; r < 4; ++r) { s1[r] = rsum16(s1[r]); s2[r] = rsum16(s2[r]); }
  if (l15 == 0) {
#pragma unroll
    for (int r = 0; r < 4; ++r) { red1[l4 * 4 + r][w] = s1[r]; red2[l4 * 4 + r][w] = s2[r]; }
  }
  __syncthreads();
  float mu[4], rs[4];
#pragma unroll
  for (int r = 0; r < 4; ++r) {
    int row = l4 * 4 + r;
    float t1 = red1[row][0] + red1[row][1] + red1[row][2] + red1[row][3];
    float t2 = red2[row][0] + red2[row][1] + red2[row][2] + red2[row][3];
    float m_ = t1 * (1.0f / 512.0f);
    float var = t2 * (1.0f / 512.0f) - m_ * m_;
    mu[r] = m_;
    rs[r] = rsqrtf(var + 1e-6f);
  }
#pragma unroll
  for (int cf = 0; cf < 8; ++cf) {
    float g = gamma[colb + cf * 16 + l15];
    float be = beta[colb + cf * 16 + l15];
#pragma unroll
    for (int r = 0; r < 4; ++r)
      io[(size_t)(row0 + l4 * 4 + r) * DM + colb + cf * 16 + l15] =
          (C[cf][r] - mu[r]) * rs[r] * g + be;
  }
}

extern "C" void kernel_launch(void* const* d_in, const int* in_sizes, int n_in,
                              void* d_out, int out_size, void* d_ws, size_t ws_size,
                              hipStream_t stream) {
  (void)in_sizes; (void)n_in; (void)out_size; (void)ws_size;
  const float* q   = (const float*)d_in[0];
  const float* k   = (const float*)d_in[1];
  const float* v   = (const float*)d_in[2];
  const int* mask  = (const int*)d_in[3];
  const float* WA  = (const float*)d_in[4];
  const float* WA2 = (const float*)d_in[5];
  const float* WA3 = (const float*)d_in[6];
  const float* fcw = (const float*)d_in[7];
  const float* gam = (const float*)d_in[8];
  const float* bet = (const float*)d_in[9];
  float* out = (float*)d_out;
  float* attn = out + (size_t)B_ * L_ * DM;

  char* ws = (char*)d_ws;
  unsigned short* WqT = (unsigned short*)ws;                                        // 64KB
  unsigned short* WvT = (unsigned short*)(ws + 65536);                              // 64KB
  unsigned short* Qp  = (unsigned short*)(ws + 131072);                             // 8MB
  unsigned short* Kb  = (unsigned short*)(ws + 131072 + 8388608);                   // 8MB
  unsigned short* VpT = (unsigned short*)(ws + 131072 + 2 * 8388608);               // 8MB
  unsigned short* FCb = (unsigned short*)(ws + 131072 + 3 * 8388608);               // 512KB
  unsigned long long* mp = (unsigned long long*)(ws + 131072 + 3 * 8388608 + 524288);  // 2MB

  k_weights<<<8, 256, 0, stream>>>(WA, WA2, WA3, WqT, WvT);
  k_conv<<<1024, 256, 0, stream>>>(k, Kb, (B_ * L_ * DM) / 4);
  k_conv<<<256, 256, 0, stream>>>(fcw, FCb, (DM * DM) / 4);
  k_maskpack<<<2048, 256, 0, stream>>>(mask, mp);
  k_qprime<<<1024, 256, 0, stream>>>(q, WqT, Qp);
  k_vprime<<<1024, 256, 0, stream>>>(v, WvT, VpT);
  k_attn<<<1024, 256, 0, stream>>>(Qp, Kb, VpT, mp, attn, out);
  k_proj<<<512, 256, 0, stream>>>(q, FCb, gam, bet, out);
}